// Round 1
// baseline (1511.834 us; speedup 1.0000x reference)
//
#include <hip/hip_runtime.h>
#include <hip/hip_bf16.h>

#define LRELU(x) ((x) >= 0.0f ? (x) : 0.01f * (x))

__device__ inline int lower_bound_i(const int* __restrict__ a, int n, int v) {
    int lo = 0, hi = n;
    while (lo < hi) {
        int m = (lo + hi) >> 1;
        if (a[m] < v) lo = m + 1; else hi = m;
    }
    return lo;
}

// ---------------------------------------------------------------------------
// Kernel 1: both MLP2 encoders (pfc: 7->32->32, vtx: 4->32->32) + sq norms.
// Block = 256 threads = 8 nodes x 32 channels. Blocks [0,1024): pfc, [1024,1280): vtx.
// ---------------------------------------------------------------------------
__launch_bounds__(256)
__global__ void encode_kernel(const float* __restrict__ x_pfc, const float* __restrict__ x_vtx,
                              const float* __restrict__ pw1, const float* __restrict__ pb1,
                              const float* __restrict__ pw2, const float* __restrict__ pb2,
                              const float* __restrict__ vw1, const float* __restrict__ vb1,
                              const float* __restrict__ vw2, const float* __restrict__ vb2,
                              float* __restrict__ pfc_enc, float* __restrict__ pfc_norm,
                              float* __restrict__ vtx_enc, float* __restrict__ vtx_norm) {
    __shared__ float h1s[8][32];
    const int t = threadIdx.x;
    const int c = t & 31;
    const int nl = t >> 5;  // node within block, 0..7

    const bool is_pfc = (blockIdx.x < 1024);
    const int node = (is_pfc ? blockIdx.x : (blockIdx.x - 1024)) * 8 + nl;
    const int din = is_pfc ? 7 : 4;
    const float* __restrict__ x  = is_pfc ? (x_pfc + node * 7) : (x_vtx + node * 4);
    const float* __restrict__ w1 = is_pfc ? pw1 : vw1;
    const float* __restrict__ b1 = is_pfc ? pb1 : vb1;
    const float* __restrict__ w2 = is_pfc ? pw2 : vw2;
    const float* __restrict__ b2 = is_pfc ? pb2 : vb2;
    float* __restrict__ enc  = is_pfc ? pfc_enc : vtx_enc;
    float* __restrict__ nrm  = is_pfc ? pfc_norm : vtx_norm;

    float h1 = b1[c];
    for (int d = 0; d < din; ++d) h1 = fmaf(x[d], w1[d * 32 + c], h1);
    h1 = LRELU(h1);
    h1s[nl][c] = h1;
    __syncthreads();

    float h2 = b2[c];
#pragma unroll
    for (int d = 0; d < 32; ++d) h2 = fmaf(h1s[nl][d], w2[d * 32 + c], h2);
    h2 = LRELU(h2);
    enc[node * 32 + c] = h2;

    // squared norm of the 32-d row (reduce over the node's 32 lanes)
    float s = h2 * h2;
#pragma unroll
    for (int m = 16; m >= 1; m >>= 1) s += __shfl_xor(s, m);
    if (c == 0) nrm[node] = s;
}

// ---------------------------------------------------------------------------
// Kernel 2/3: fused kNN(K=16, group-local) + edge conv + max-pool.
// One wave (64 lanes) per dst node. Candidates (distance, idx) live in
// registers (CAND slots/lane -> capacity 64*CAND src per group).
// Conv is fused into the selection loop: the argmin winner is wave-uniform.
// ---------------------------------------------------------------------------
template <int CAND, bool WRITE_NORM>
__launch_bounds__(256)
__global__ void edge_conv_kernel(const float* __restrict__ dstf, const float* __restrict__ dstn,
                                 const float* __restrict__ srcf, const float* __restrict__ srcn,
                                 const int* __restrict__ bdst, const int* __restrict__ bsrc,
                                 int Nd, int Ns,
                                 const float* __restrict__ W, const float* __restrict__ B,
                                 float* __restrict__ outf, float* __restrict__ outn) {
    __shared__ float sW[64 * 32];
    __shared__ float sB[32];
    const int t = threadIdx.x;
    for (int k = t; k < 2048; k += 256) sW[k] = W[k];
    if (t < 32) sB[t] = B[t];
    __syncthreads();

    const int lane = t & 63;
    const int i = blockIdx.x * 4 + (t >> 6);
    if (i >= Nd) return;

    const int g = bdst[i];
    const int start = lower_bound_i(bsrc, Ns, g);
    const int end   = lower_bound_i(bsrc, Ns, g + 1);

    // dst features into registers
    float xi[32];
    {
        const float4* xr = reinterpret_cast<const float4*>(dstf + (size_t)i * 32);
#pragma unroll
        for (int q = 0; q < 8; ++q) {
            float4 v = xr[q];
            xi[4 * q + 0] = v.x; xi[4 * q + 1] = v.y;
            xi[4 * q + 2] = v.z; xi[4 * q + 3] = v.w;
        }
    }
    const float ni = dstn[i];
    const float FINF = __builtin_huge_valf();

    // distance phase: d2 = |dst|^2 + |src|^2 - 2*dot  (matches reference formula)
    float cd[CAND];
    int   ci[CAND];
#pragma unroll
    for (int s = 0; s < CAND; ++s) {
        int j = start + lane + s * 64;
        if (j < end) {
            const float4* rr = reinterpret_cast<const float4*>(srcf + (size_t)j * 32);
            float dot = 0.0f;
#pragma unroll
            for (int q = 0; q < 8; ++q) {
                float4 v = rr[q];
                dot = fmaf(v.x, xi[4 * q + 0], dot);
                dot = fmaf(v.y, xi[4 * q + 1], dot);
                dot = fmaf(v.z, xi[4 * q + 2], dot);
                dot = fmaf(v.w, xi[4 * q + 3], dot);
            }
            cd[s] = ni + srcn[j] - 2.0f * dot;
            ci[s] = j;
        } else {
            cd[s] = FINF;
            ci[s] = 0x7fffffff;
        }
    }

    // base[c] = b[c] + sum_d xi[d]*W[d][c]  (first 32 rows of W)
    const int c = lane & 31;
    float base = sB[c];
#pragma unroll
    for (int d = 0; d < 32; ++d) base = fmaf(xi[d], sW[d * 32 + c], base);

    float vmax = -FINF;
#pragma unroll
    for (int k = 0; k < 16; ++k) {
        // local argmin over candidate slots (tie -> smaller index, matches top_k)
        float bd = cd[0];
        int   bi = ci[0];
#pragma unroll
        for (int s = 1; s < CAND; ++s)
            if (cd[s] < bd || (cd[s] == bd && ci[s] < bi)) { bd = cd[s]; bi = ci[s]; }
        // wave butterfly argmin
#pragma unroll
        for (int m = 32; m >= 1; m >>= 1) {
            float od = __shfl_xor(bd, m);
            int   oi = __shfl_xor(bi, m);
            if (od < bd || (od == bd && oi < bi)) { bd = od; bi = oi; }
        }
        // invalidate winner in its owner's slot
#pragma unroll
        for (int s = 0; s < CAND; ++s)
            if (ci[s] == bi) cd[s] = FINF;

        int j = (bi >= 0 && bi < Ns) ? bi : (start < Ns ? start : 0);  // safety clamp
        const float4* rr = reinterpret_cast<const float4*>(srcf + (size_t)j * 32);
        float acc = base;
#pragma unroll
        for (int q = 0; q < 8; ++q) {
            float4 v = rr[q];
            acc = fmaf(v.x - xi[4 * q + 0], sW[(32 + 4 * q + 0) * 32 + c], acc);
            acc = fmaf(v.y - xi[4 * q + 1], sW[(32 + 4 * q + 1) * 32 + c], acc);
            acc = fmaf(v.z - xi[4 * q + 2], sW[(32 + 4 * q + 2) * 32 + c], acc);
            acc = fmaf(v.w - xi[4 * q + 3], sW[(32 + 4 * q + 3) * 32 + c], acc);
        }
        float h = LRELU(acc);
        vmax = fmaxf(vmax, h);
    }

    if (lane < 32) outf[(size_t)i * 32 + c] = vmax;
    if (WRITE_NORM) {
        float s2 = vmax * vmax;
#pragma unroll
        for (int m = 16; m >= 1; m >>= 1) s2 += __shfl_xor(s2, m);
        if (lane == 0) outn[i] = s2;
    }
}

// ---------------------------------------------------------------------------
// Kernel 4: output MLP 32 -> 64 -> 32 -> 4 -> 1 (lrelu each) + batch copy.
// One wave per node, 4 waves/block, grid exactly covers N (uniform barriers).
// ---------------------------------------------------------------------------
__launch_bounds__(256)
__global__ void out_mlp_kernel(const float* __restrict__ f2, const int* __restrict__ bpfc,
                               const float* __restrict__ w1, const float* __restrict__ b1,
                               const float* __restrict__ w2, const float* __restrict__ b2,
                               const float* __restrict__ w3, const float* __restrict__ b3,
                               const float* __restrict__ w4, const float* __restrict__ b4,
                               float* __restrict__ dout, int N) {
    __shared__ float sW1[32 * 64], sW2[64 * 32], sW3[32 * 4];
    __shared__ float sB1[64], sB2[32], sB3[4], sW4[4], sB4[1];
    __shared__ float ex1[4][64];
    __shared__ float ex2[4][32];

    const int t = threadIdx.x;
    for (int k = t; k < 2048; k += 256) { sW1[k] = w1[k]; sW2[k] = w2[k]; }
    if (t < 128) sW3[t] = w3[t];
    if (t < 64)  sB1[t] = b1[t];
    if (t < 32)  sB2[t] = b2[t];
    if (t < 4)   { sB3[t] = b3[t]; sW4[t] = w4[t]; }
    if (t == 0)  sB4[0] = b4[0];
    __syncthreads();

    const int w = t >> 6;
    const int lane = t & 63;
    const int i = blockIdx.x * 4 + w;

    // load the node's 32-d feature row (wave-uniform broadcast loads)
    float ff[32];
    {
        const float4* fr = reinterpret_cast<const float4*>(f2 + (size_t)i * 32);
#pragma unroll
        for (int q = 0; q < 8; ++q) {
            float4 v = fr[q];
            ff[4 * q + 0] = v.x; ff[4 * q + 1] = v.y;
            ff[4 * q + 2] = v.z; ff[4 * q + 3] = v.w;
        }
    }

    // layer 1: 64 outputs, one per lane
    float h1 = sB1[lane];
#pragma unroll
    for (int d = 0; d < 32; ++d) h1 = fmaf(ff[d], sW1[d * 64 + lane], h1);
    h1 = LRELU(h1);
    ex1[w][lane] = h1;
    __syncthreads();

    // layer 2: 32 outputs (both halves compute duplicates)
    const int c = lane & 31;
    float h2 = sB2[c];
#pragma unroll
    for (int d = 0; d < 64; ++d) h2 = fmaf(ex1[w][d], sW2[d * 32 + c], h2);
    h2 = LRELU(h2);
    if (lane < 32) ex2[w][c] = h2;
    __syncthreads();

    // layers 3+4: tiny, every lane computes the full thing
    float h3[4];
#pragma unroll
    for (int q = 0; q < 4; ++q) {
        float a = sB3[q];
#pragma unroll
        for (int d = 0; d < 32; ++d) a = fmaf(ex2[w][d], sW3[d * 4 + q], a);
        h3[q] = LRELU(a);
    }
    float o = sB4[0];
#pragma unroll
    for (int q = 0; q < 4; ++q) o = fmaf(h3[q], sW4[q], o);
    o = LRELU(o);

    if (lane == 0) dout[i] = o;                       // output 0: (8192,1)
    if (lane == 1) dout[N + i] = (float)bpfc[i];      // output 1: batch_pfc
}

// ---------------------------------------------------------------------------
extern "C" void kernel_launch(void* const* d_in, const int* in_sizes, int n_in,
                              void* d_out, int out_size, void* d_ws, size_t ws_size,
                              hipStream_t stream) {
    const float* x_pfc     = (const float*)d_in[0];
    const float* x_vtx     = (const float*)d_in[1];
    const int*   batch_pfc = (const int*)d_in[2];
    const int*   batch_vtx = (const int*)d_in[3];
    const float* pfc_w1 = (const float*)d_in[4];
    const float* pfc_b1 = (const float*)d_in[5];
    const float* pfc_w2 = (const float*)d_in[6];
    const float* pfc_b2 = (const float*)d_in[7];
    const float* vtx_w1 = (const float*)d_in[8];
    const float* vtx_b1 = (const float*)d_in[9];
    const float* vtx_w2 = (const float*)d_in[10];
    const float* vtx_b2 = (const float*)d_in[11];
    const float* conv_w = (const float*)d_in[12];
    const float* conv_b = (const float*)d_in[13];
    const float* out_w1 = (const float*)d_in[14];
    const float* out_b1 = (const float*)d_in[15];
    const float* out_w2 = (const float*)d_in[16];
    const float* out_b2 = (const float*)d_in[17];
    const float* out_w3 = (const float*)d_in[18];
    const float* out_b3 = (const float*)d_in[19];
    const float* out_w4 = (const float*)d_in[20];
    const float* out_b4 = (const float*)d_in[21];

    const int N_PFC = 8192, N_VTX = 2048;

    float* ws = (float*)d_ws;
    float* pfc_enc = ws;                 // 8192*32
    float* vtx_enc = ws + 262144;        // 2048*32
    float* feats1  = ws + 327680;        // 8192*32
    float* feats2  = ws + 589824;        // 8192*32
    float* n_pfc   = ws + 851968;        // 8192
    float* n_vtx   = ws + 860160;        // 2048
    float* n_f1    = ws + 862208;        // 8192

    encode_kernel<<<1280, 256, 0, stream>>>(x_pfc, x_vtx,
                                            pfc_w1, pfc_b1, pfc_w2, pfc_b2,
                                            vtx_w1, vtx_b1, vtx_w2, vtx_b2,
                                            pfc_enc, n_pfc, vtx_enc, n_vtx);

    // conv1: src = dst = pfc_enc (group sizes ~256, capacity 8*64=512)
    edge_conv_kernel<8, true><<<2048, 256, 0, stream>>>(
        pfc_enc, n_pfc, pfc_enc, n_pfc, batch_pfc, batch_pfc,
        N_PFC, N_PFC, conv_w, conv_b, feats1, n_f1);

    // conv2: dst = feats1 (batch_pfc), src = vtx_enc (batch_vtx, ~64/group, cap 256)
    edge_conv_kernel<4, false><<<2048, 256, 0, stream>>>(
        feats1, n_f1, vtx_enc, n_vtx, batch_pfc, batch_vtx,
        N_PFC, N_VTX, conv_w, conv_b, feats2, nullptr);

    out_mlp_kernel<<<2048, 256, 0, stream>>>(feats2, batch_pfc,
                                             out_w1, out_b1, out_w2, out_b2,
                                             out_w3, out_b3, out_w4, out_b4,
                                             (float*)d_out, N_PFC);
}

// Round 2
// 536.635 us; speedup vs baseline: 2.8172x; 2.8172x over previous
//
#include <hip/hip_runtime.h>
#include <hip/hip_bf16.h>

#define LRELU(x) ((x) >= 0.0f ? (x) : 0.01f * (x))

__device__ inline int lower_bound_i(const int* __restrict__ a, int n, int v) {
    int lo = 0, hi = n;
    while (lo < hi) {
        int m = (lo + hi) >> 1;
        if (a[m] < v) lo = m + 1; else hi = m;
    }
    return lo;
}

// ---------------------------------------------------------------------------
// Kernel 1: both MLP2 encoders (pfc: 7->32->32, vtx: 4->32->32) + sq norms.
// Block = 256 threads = 8 nodes x 32 channels. Blocks [0,1024): pfc, [1024,1280): vtx.
// ---------------------------------------------------------------------------
__launch_bounds__(256)
__global__ void encode_kernel(const float* __restrict__ x_pfc, const float* __restrict__ x_vtx,
                              const float* __restrict__ pw1, const float* __restrict__ pb1,
                              const float* __restrict__ pw2, const float* __restrict__ pb2,
                              const float* __restrict__ vw1, const float* __restrict__ vb1,
                              const float* __restrict__ vw2, const float* __restrict__ vb2,
                              float* __restrict__ pfc_enc, float* __restrict__ pfc_norm,
                              float* __restrict__ vtx_enc, float* __restrict__ vtx_norm) {
    __shared__ float h1s[8][32];
    const int t = threadIdx.x;
    const int c = t & 31;
    const int nl = t >> 5;  // node within block, 0..7

    const bool is_pfc = (blockIdx.x < 1024);
    const int node = (is_pfc ? blockIdx.x : (blockIdx.x - 1024)) * 8 + nl;
    const int din = is_pfc ? 7 : 4;
    const float* __restrict__ x  = is_pfc ? (x_pfc + node * 7) : (x_vtx + node * 4);
    const float* __restrict__ w1 = is_pfc ? pw1 : vw1;
    const float* __restrict__ b1 = is_pfc ? pb1 : vb1;
    const float* __restrict__ w2 = is_pfc ? pw2 : vw2;
    const float* __restrict__ b2 = is_pfc ? pb2 : vb2;
    float* __restrict__ enc  = is_pfc ? pfc_enc : vtx_enc;
    float* __restrict__ nrm  = is_pfc ? pfc_norm : vtx_norm;

    float h1 = b1[c];
    for (int d = 0; d < din; ++d) h1 = fmaf(x[d], w1[d * 32 + c], h1);
    h1 = LRELU(h1);
    h1s[nl][c] = h1;
    __syncthreads();

    float h2 = b2[c];
#pragma unroll
    for (int d = 0; d < 32; ++d) h2 = fmaf(h1s[nl][d], w2[d * 32 + c], h2);
    h2 = LRELU(h2);
    enc[node * 32 + c] = h2;

    // squared norm of the 32-d row (reduce over the node's 32 lanes)
    float s = h2 * h2;
#pragma unroll
    for (int m = 16; m >= 1; m >>= 1) s += __shfl_xor(s, m);
    if (c == 0) nrm[node] = s;
}

// ---------------------------------------------------------------------------
// Kernel 2/3: fused kNN(K=16, group-local) + edge conv + max-pool.
// One wave per dst node. Phase 1: distances into CAND register slots/lane.
// Phase 2: 16 wave-argmin rounds (tie -> smaller idx, matches top_k), winner
// indices stored in per-wave LDS. Phase 3: conv with TWO neighbors per round
// (half-wave each), cross-half max at the end.
// Unrolling deliberately bounded: round-1 full-unroll spilled to 1.7 GB of
// scratch HBM traffic (VGPR=256). __launch_bounds__(256,4) caps at 128 VGPR.
// ---------------------------------------------------------------------------
template <int CAND, bool WRITE_NORM>
__launch_bounds__(256, 4)
__global__ void edge_conv_kernel(const float* __restrict__ dstf, const float* __restrict__ dstn,
                                 const float* __restrict__ srcf, const float* __restrict__ srcn,
                                 const int* __restrict__ bdst, const int* __restrict__ bsrc,
                                 int Nd, int Ns,
                                 const float* __restrict__ W, const float* __restrict__ B,
                                 float* __restrict__ outf, float* __restrict__ outn) {
    __shared__ float sW[64 * 32];
    __shared__ float sB[32];
    __shared__ int   widx[4][16];
    const int t = threadIdx.x;
    for (int k = t; k < 2048; k += 256) sW[k] = W[k];
    if (t < 32) sB[t] = B[t];
    __syncthreads();

    const int lane = t & 63;
    const int w = t >> 6;
    const int i = blockIdx.x * 4 + w;
    if (i >= Nd) return;

    const int g = bdst[i];
    const int start = lower_bound_i(bsrc, Ns, g);
    const int end   = lower_bound_i(bsrc, Ns, g + 1);

    // dst features into registers
    float xi[32];
    {
        const float4* xr = reinterpret_cast<const float4*>(dstf + (size_t)i * 32);
#pragma unroll
        for (int q = 0; q < 8; ++q) {
            float4 v = xr[q];
            xi[4 * q + 0] = v.x; xi[4 * q + 1] = v.y;
            xi[4 * q + 2] = v.z; xi[4 * q + 3] = v.w;
        }
    }
    const float ni = dstn[i];
    const float FINF = __builtin_huge_valf();

    // Phase 1: d2 = |dst|^2 + |src|^2 - 2*dot  (matches reference formula)
    float cd[CAND];
    int   ci[CAND];
#pragma unroll
    for (int s = 0; s < CAND; ++s) { cd[s] = FINF; ci[s] = 0x7fffffff; }
#pragma unroll 2
    for (int s = 0; s < CAND; ++s) {
        int j = start + lane + s * 64;
        if (j < end) {
            const float4* rr = reinterpret_cast<const float4*>(srcf + (size_t)j * 32);
            float dot = 0.0f;
#pragma unroll
            for (int q = 0; q < 8; ++q) {
                float4 v = rr[q];
                dot = fmaf(v.x, xi[4 * q + 0], dot);
                dot = fmaf(v.y, xi[4 * q + 1], dot);
                dot = fmaf(v.z, xi[4 * q + 2], dot);
                dot = fmaf(v.w, xi[4 * q + 3], dot);
            }
            cd[s] = ni + srcn[j] - 2.0f * dot;
            ci[s] = j;
        }
    }

    // Phase 2: 16 argmin rounds; winners to per-wave LDS (no block barrier needed)
#pragma unroll 1
    for (int k = 0; k < 16; ++k) {
        float bd = cd[0];
        int   bi = ci[0];
#pragma unroll
        for (int s = 1; s < CAND; ++s)
            if (cd[s] < bd || (cd[s] == bd && ci[s] < bi)) { bd = cd[s]; bi = ci[s]; }
#pragma unroll
        for (int m = 32; m >= 1; m >>= 1) {
            float od = __shfl_xor(bd, m);
            int   oi = __shfl_xor(bi, m);
            if (od < bd || (od == bd && oi < bi)) { bd = od; bi = oi; }
        }
#pragma unroll
        for (int s = 0; s < CAND; ++s)
            if (ci[s] == bi) cd[s] = FINF;
        if (lane == 0) widx[w][k] = bi;
    }

    // base[c] = b[c] + sum_d xi[d]*W[d][c]  (first 32 rows of W)
    const int c = lane & 31;
    float base = sB[c];
#pragma unroll
    for (int d = 0; d < 32; ++d) base = fmaf(xi[d], sW[d * 32 + c], base);

    // Phase 3: conv, two neighbors per round (lane<32 -> even k, else odd k)
    const int half = lane >> 5;
    float vmax = -FINF;
#pragma unroll 1
    for (int r = 0; r < 8; ++r) {
        int bi = widx[w][2 * r + half];
        int j = (bi >= 0 && bi < Ns) ? bi : (start < Ns ? start : 0);  // safety clamp
        const float4* rr = reinterpret_cast<const float4*>(srcf + (size_t)j * 32);
        float acc = base;
#pragma unroll
        for (int q = 0; q < 8; ++q) {
            float4 v = rr[q];
            acc = fmaf(v.x - xi[4 * q + 0], sW[(32 + 4 * q + 0) * 32 + c], acc);
            acc = fmaf(v.y - xi[4 * q + 1], sW[(32 + 4 * q + 1) * 32 + c], acc);
            acc = fmaf(v.z - xi[4 * q + 2], sW[(32 + 4 * q + 2) * 32 + c], acc);
            acc = fmaf(v.w - xi[4 * q + 3], sW[(32 + 4 * q + 3) * 32 + c], acc);
        }
        vmax = fmaxf(vmax, LRELU(acc));
    }
    vmax = fmaxf(vmax, __shfl_xor(vmax, 32));  // combine the two halves

    if (lane < 32) outf[(size_t)i * 32 + c] = vmax;
    if (WRITE_NORM) {
        float s2 = vmax * vmax;
#pragma unroll
        for (int m = 16; m >= 1; m >>= 1) s2 += __shfl_xor(s2, m);
        if (lane == 0) outn[i] = s2;
    }
}

// ---------------------------------------------------------------------------
// Kernel 4: output MLP 32 -> 64 -> 32 -> 4 -> 1 (lrelu each) + batch copy.
// One wave per node, 4 waves/block, grid exactly covers N (uniform barriers).
// ---------------------------------------------------------------------------
__launch_bounds__(256)
__global__ void out_mlp_kernel(const float* __restrict__ f2, const int* __restrict__ bpfc,
                               const float* __restrict__ w1, const float* __restrict__ b1,
                               const float* __restrict__ w2, const float* __restrict__ b2,
                               const float* __restrict__ w3, const float* __restrict__ b3,
                               const float* __restrict__ w4, const float* __restrict__ b4,
                               float* __restrict__ dout, int N) {
    __shared__ float sW1[32 * 64], sW2[64 * 32], sW3[32 * 4];
    __shared__ float sB1[64], sB2[32], sB3[4], sW4[4], sB4[1];
    __shared__ float ex1[4][64];
    __shared__ float ex2[4][32];

    const int t = threadIdx.x;
    for (int k = t; k < 2048; k += 256) { sW1[k] = w1[k]; sW2[k] = w2[k]; }
    if (t < 128) sW3[t] = w3[t];
    if (t < 64)  sB1[t] = b1[t];
    if (t < 32)  sB2[t] = b2[t];
    if (t < 4)   { sB3[t] = b3[t]; sW4[t] = w4[t]; }
    if (t == 0)  sB4[0] = b4[0];
    __syncthreads();

    const int w = t >> 6;
    const int lane = t & 63;
    const int i = blockIdx.x * 4 + w;

    // load the node's 32-d feature row (wave-uniform broadcast loads)
    float ff[32];
    {
        const float4* fr = reinterpret_cast<const float4*>(f2 + (size_t)i * 32);
#pragma unroll
        for (int q = 0; q < 8; ++q) {
            float4 v = fr[q];
            ff[4 * q + 0] = v.x; ff[4 * q + 1] = v.y;
            ff[4 * q + 2] = v.z; ff[4 * q + 3] = v.w;
        }
    }

    // layer 1: 64 outputs, one per lane
    float h1 = sB1[lane];
#pragma unroll
    for (int d = 0; d < 32; ++d) h1 = fmaf(ff[d], sW1[d * 64 + lane], h1);
    h1 = LRELU(h1);
    ex1[w][lane] = h1;
    __syncthreads();

    // layer 2: 32 outputs (both halves compute duplicates)
    const int c = lane & 31;
    float h2 = sB2[c];
#pragma unroll
    for (int d = 0; d < 64; ++d) h2 = fmaf(ex1[w][d], sW2[d * 32 + c], h2);
    h2 = LRELU(h2);
    if (lane < 32) ex2[w][c] = h2;
    __syncthreads();

    // layers 3+4: tiny, every lane computes the full thing
    float h3[4];
#pragma unroll
    for (int q = 0; q < 4; ++q) {
        float a = sB3[q];
#pragma unroll
        for (int d = 0; d < 32; ++d) a = fmaf(ex2[w][d], sW3[d * 4 + q], a);
        h3[q] = LRELU(a);
    }
    float o = sB4[0];
#pragma unroll
    for (int q = 0; q < 4; ++q) o = fmaf(h3[q], sW4[q], o);
    o = LRELU(o);

    if (lane == 0) dout[i] = o;                       // output 0: (8192,1)
    if (lane == 1) dout[N + i] = (float)bpfc[i];      // output 1: batch_pfc
}

// ---------------------------------------------------------------------------
extern "C" void kernel_launch(void* const* d_in, const int* in_sizes, int n_in,
                              void* d_out, int out_size, void* d_ws, size_t ws_size,
                              hipStream_t stream) {
    const float* x_pfc     = (const float*)d_in[0];
    const float* x_vtx     = (const float*)d_in[1];
    const int*   batch_pfc = (const int*)d_in[2];
    const int*   batch_vtx = (const int*)d_in[3];
    const float* pfc_w1 = (const float*)d_in[4];
    const float* pfc_b1 = (const float*)d_in[5];
    const float* pfc_w2 = (const float*)d_in[6];
    const float* pfc_b2 = (const float*)d_in[7];
    const float* vtx_w1 = (const float*)d_in[8];
    const float* vtx_b1 = (const float*)d_in[9];
    const float* vtx_w2 = (const float*)d_in[10];
    const float* vtx_b2 = (const float*)d_in[11];
    const float* conv_w = (const float*)d_in[12];
    const float* conv_b = (const float*)d_in[13];
    const float* out_w1 = (const float*)d_in[14];
    const float* out_b1 = (const float*)d_in[15];
    const float* out_w2 = (const float*)d_in[16];
    const float* out_b2 = (const float*)d_in[17];
    const float* out_w3 = (const float*)d_in[18];
    const float* out_b3 = (const float*)d_in[19];
    const float* out_w4 = (const float*)d_in[20];
    const float* out_b4 = (const float*)d_in[21];

    const int N_PFC = 8192, N_VTX = 2048;

    float* ws = (float*)d_ws;
    float* pfc_enc = ws;                 // 8192*32
    float* vtx_enc = ws + 262144;        // 2048*32
    float* feats1  = ws + 327680;        // 8192*32
    float* feats2  = ws + 589824;        // 8192*32
    float* n_pfc   = ws + 851968;        // 8192
    float* n_vtx   = ws + 860160;        // 2048
    float* n_f1    = ws + 862208;        // 8192

    encode_kernel<<<1280, 256, 0, stream>>>(x_pfc, x_vtx,
                                            pfc_w1, pfc_b1, pfc_w2, pfc_b2,
                                            vtx_w1, vtx_b1, vtx_w2, vtx_b2,
                                            pfc_enc, n_pfc, vtx_enc, n_vtx);

    // conv1: src = dst = pfc_enc (group sizes ~256±16, capacity 6*64=384)
    edge_conv_kernel<6, true><<<2048, 256, 0, stream>>>(
        pfc_enc, n_pfc, pfc_enc, n_pfc, batch_pfc, batch_pfc,
        N_PFC, N_PFC, conv_w, conv_b, feats1, n_f1);

    // conv2: dst = feats1 (batch_pfc), src = vtx_enc (~64±8/group, cap 192)
    edge_conv_kernel<3, false><<<2048, 256, 0, stream>>>(
        feats1, n_f1, vtx_enc, n_vtx, batch_pfc, batch_vtx,
        N_PFC, N_VTX, conv_w, conv_b, feats2, nullptr);

    out_mlp_kernel<<<2048, 256, 0, stream>>>(feats2, batch_pfc,
                                             out_w1, out_b1, out_w2, out_b2,
                                             out_w3, out_b3, out_w4, out_b4,
                                             (float*)d_out, N_PFC);
}

// Round 3
// 429.436 us; speedup vs baseline: 3.5205x; 1.2496x over previous
//
#include <hip/hip_runtime.h>
#include <hip/hip_bf16.h>

#define LRELU(x) ((x) >= 0.0f ? (x) : 0.01f * (x))

__device__ inline int lower_bound_i(const int* __restrict__ a, int n, int v) {
    int lo = 0, hi = n;
    while (lo < hi) {
        int m = (lo + hi) >> 1;
        if (a[m] < v) lo = m + 1; else hi = m;
    }
    return lo;
}

// ---------------------------------------------------------------------------
// Kernel 1: both MLP2 encoders (pfc: 7->32->32, vtx: 4->32->32) + sq norms.
// Block = 256 threads = 8 nodes x 32 channels. Blocks [0,1024): pfc, [1024,1280): vtx.
// ---------------------------------------------------------------------------
__launch_bounds__(256)
__global__ void encode_kernel(const float* __restrict__ x_pfc, const float* __restrict__ x_vtx,
                              const float* __restrict__ pw1, const float* __restrict__ pb1,
                              const float* __restrict__ pw2, const float* __restrict__ pb2,
                              const float* __restrict__ vw1, const float* __restrict__ vb1,
                              const float* __restrict__ vw2, const float* __restrict__ vb2,
                              float* __restrict__ pfc_enc, float* __restrict__ pfc_norm,
                              float* __restrict__ vtx_enc, float* __restrict__ vtx_norm) {
    __shared__ float h1s[8][32];
    const int t = threadIdx.x;
    const int c = t & 31;
    const int nl = t >> 5;  // node within block, 0..7

    const bool is_pfc = (blockIdx.x < 1024);
    const int node = (is_pfc ? blockIdx.x : (blockIdx.x - 1024)) * 8 + nl;
    const int din = is_pfc ? 7 : 4;
    const float* __restrict__ x  = is_pfc ? (x_pfc + node * 7) : (x_vtx + node * 4);
    const float* __restrict__ w1 = is_pfc ? pw1 : vw1;
    const float* __restrict__ b1 = is_pfc ? pb1 : vb1;
    const float* __restrict__ w2 = is_pfc ? pw2 : vw2;
    const float* __restrict__ b2 = is_pfc ? pb2 : vb2;
    float* __restrict__ enc  = is_pfc ? pfc_enc : vtx_enc;
    float* __restrict__ nrm  = is_pfc ? pfc_norm : vtx_norm;

    float h1 = b1[c];
    for (int d = 0; d < din; ++d) h1 = fmaf(x[d], w1[d * 32 + c], h1);
    h1 = LRELU(h1);
    h1s[nl][c] = h1;
    __syncthreads();

    float h2 = b2[c];
#pragma unroll
    for (int d = 0; d < 32; ++d) h2 = fmaf(h1s[nl][d], w2[d * 32 + c], h2);
    h2 = LRELU(h2);
    enc[node * 32 + c] = h2;

    // squared norm of the 32-d row (reduce over the node's 32 lanes)
    float s = h2 * h2;
#pragma unroll
    for (int m = 16; m >= 1; m >>= 1) s += __shfl_xor(s, m);
    if (c == 0) nrm[node] = s;
}

// ---------------------------------------------------------------------------
// Kernel 2/3: fused kNN(K=16, group-local) + edge conv + max-pool.
// One wave per dst node. Phase 1: distances into CAND register slots/lane.
// Phase 2: 16 wave-argmin rounds (tie -> smaller idx, matches top_k), winner
// indices stored in per-wave LDS. Phase 3: conv with TWO neighbors per round
// (half-wave each), cross-half max at the end.
// NOTE: Phase 1 MUST be fully unrolled — any dynamic index into cd[]/ci[]
// demotes the arrays to scratch (round-2: 624 MB HBM scratch traffic from
// `#pragma unroll 2`). Conv loop stays unroll-1 (round-1: full unroll there
// blew 256 VGPRs). __launch_bounds__(256,4) caps at 128 VGPR.
// ---------------------------------------------------------------------------
template <int CAND, bool WRITE_NORM>
__launch_bounds__(256, 4)
__global__ void edge_conv_kernel(const float* __restrict__ dstf, const float* __restrict__ dstn,
                                 const float* __restrict__ srcf, const float* __restrict__ srcn,
                                 const int* __restrict__ bdst, const int* __restrict__ bsrc,
                                 int Nd, int Ns,
                                 const float* __restrict__ W, const float* __restrict__ B,
                                 float* __restrict__ outf, float* __restrict__ outn) {
    __shared__ float sW[64 * 32];
    __shared__ float sB[32];
    __shared__ int   widx[4][16];
    const int t = threadIdx.x;
    for (int k = t; k < 2048; k += 256) sW[k] = W[k];
    if (t < 32) sB[t] = B[t];
    __syncthreads();

    const int lane = t & 63;
    const int w = t >> 6;
    const int i = blockIdx.x * 4 + w;
    if (i >= Nd) return;

    const int g = bdst[i];
    const int start = lower_bound_i(bsrc, Ns, g);
    const int end   = lower_bound_i(bsrc, Ns, g + 1);

    // dst features into registers
    float xi[32];
    {
        const float4* xr = reinterpret_cast<const float4*>(dstf + (size_t)i * 32);
#pragma unroll
        for (int q = 0; q < 8; ++q) {
            float4 v = xr[q];
            xi[4 * q + 0] = v.x; xi[4 * q + 1] = v.y;
            xi[4 * q + 2] = v.z; xi[4 * q + 3] = v.w;
        }
    }
    const float ni = dstn[i];
    const float FINF = __builtin_huge_valf();

    // Phase 1: d2 = |dst|^2 + |src|^2 - 2*dot  (matches reference formula)
    // FULLY unrolled so cd/ci stay register-resident.
    float cd[CAND];
    int   ci[CAND];
#pragma unroll
    for (int s = 0; s < CAND; ++s) {
        int j = start + lane + s * 64;
        if (j < end) {
            const float4* rr = reinterpret_cast<const float4*>(srcf + (size_t)j * 32);
            float dot = 0.0f;
#pragma unroll
            for (int q = 0; q < 8; ++q) {
                float4 v = rr[q];
                dot = fmaf(v.x, xi[4 * q + 0], dot);
                dot = fmaf(v.y, xi[4 * q + 1], dot);
                dot = fmaf(v.z, xi[4 * q + 2], dot);
                dot = fmaf(v.w, xi[4 * q + 3], dot);
            }
            cd[s] = ni + srcn[j] - 2.0f * dot;
            ci[s] = j;
        } else {
            cd[s] = FINF;
            ci[s] = 0x7fffffff;
        }
    }

    // Phase 2: 16 argmin rounds; winners to per-wave LDS (no block barrier needed)
#pragma unroll 1
    for (int k = 0; k < 16; ++k) {
        float bd = cd[0];
        int   bi = ci[0];
#pragma unroll
        for (int s = 1; s < CAND; ++s)
            if (cd[s] < bd || (cd[s] == bd && ci[s] < bi)) { bd = cd[s]; bi = ci[s]; }
#pragma unroll
        for (int m = 32; m >= 1; m >>= 1) {
            float od = __shfl_xor(bd, m);
            int   oi = __shfl_xor(bi, m);
            if (od < bd || (od == bd && oi < bi)) { bd = od; bi = oi; }
        }
#pragma unroll
        for (int s = 0; s < CAND; ++s)
            if (ci[s] == bi) cd[s] = FINF;
        if (lane == 0) widx[w][k] = bi;
    }

    // base[c] = b[c] + sum_d xi[d]*W[d][c]  (first 32 rows of W)
    const int c = lane & 31;
    float base = sB[c];
#pragma unroll
    for (int d = 0; d < 32; ++d) base = fmaf(xi[d], sW[d * 32 + c], base);

    // Phase 3: conv, two neighbors per round (lane<32 -> even k, else odd k)
    const int half = lane >> 5;
    float vmax = -FINF;
#pragma unroll 1
    for (int r = 0; r < 8; ++r) {
        int bi = widx[w][2 * r + half];
        int j = (bi >= 0 && bi < Ns) ? bi : (start < Ns ? start : 0);  // safety clamp
        const float4* rr = reinterpret_cast<const float4*>(srcf + (size_t)j * 32);
        float acc = base;
#pragma unroll
        for (int q = 0; q < 8; ++q) {
            float4 v = rr[q];
            acc = fmaf(v.x - xi[4 * q + 0], sW[(32 + 4 * q + 0) * 32 + c], acc);
            acc = fmaf(v.y - xi[4 * q + 1], sW[(32 + 4 * q + 1) * 32 + c], acc);
            acc = fmaf(v.z - xi[4 * q + 2], sW[(32 + 4 * q + 2) * 32 + c], acc);
            acc = fmaf(v.w - xi[4 * q + 3], sW[(32 + 4 * q + 3) * 32 + c], acc);
        }
        vmax = fmaxf(vmax, LRELU(acc));
    }
    vmax = fmaxf(vmax, __shfl_xor(vmax, 32));  // combine the two halves

    if (lane < 32) outf[(size_t)i * 32 + c] = vmax;
    if (WRITE_NORM) {
        float s2 = vmax * vmax;
#pragma unroll
        for (int m = 16; m >= 1; m >>= 1) s2 += __shfl_xor(s2, m);
        if (lane == 0) outn[i] = s2;
    }
}

// ---------------------------------------------------------------------------
// Kernel 4: output MLP 32 -> 64 -> 32 -> 4 -> 1 (lrelu each) + batch copy.
// One wave per node, 4 waves/block, grid exactly covers N (uniform barriers).
// ---------------------------------------------------------------------------
__launch_bounds__(256)
__global__ void out_mlp_kernel(const float* __restrict__ f2, const int* __restrict__ bpfc,
                               const float* __restrict__ w1, const float* __restrict__ b1,
                               const float* __restrict__ w2, const float* __restrict__ b2,
                               const float* __restrict__ w3, const float* __restrict__ b3,
                               const float* __restrict__ w4, const float* __restrict__ b4,
                               float* __restrict__ dout, int N) {
    __shared__ float sW1[32 * 64], sW2[64 * 32], sW3[32 * 4];
    __shared__ float sB1[64], sB2[32], sB3[4], sW4[4], sB4[1];
    __shared__ float ex1[4][64];
    __shared__ float ex2[4][32];

    const int t = threadIdx.x;
    for (int k = t; k < 2048; k += 256) { sW1[k] = w1[k]; sW2[k] = w2[k]; }
    if (t < 128) sW3[t] = w3[t];
    if (t < 64)  sB1[t] = b1[t];
    if (t < 32)  sB2[t] = b2[t];
    if (t < 4)   { sB3[t] = b3[t]; sW4[t] = w4[t]; }
    if (t == 0)  sB4[0] = b4[0];
    __syncthreads();

    const int w = t >> 6;
    const int lane = t & 63;
    const int i = blockIdx.x * 4 + w;

    // load the node's 32-d feature row (wave-uniform broadcast loads)
    float ff[32];
    {
        const float4* fr = reinterpret_cast<const float4*>(f2 + (size_t)i * 32);
#pragma unroll
        for (int q = 0; q < 8; ++q) {
            float4 v = fr[q];
            ff[4 * q + 0] = v.x; ff[4 * q + 1] = v.y;
            ff[4 * q + 2] = v.z; ff[4 * q + 3] = v.w;
        }
    }

    // layer 1: 64 outputs, one per lane
    float h1 = sB1[lane];
#pragma unroll
    for (int d = 0; d < 32; ++d) h1 = fmaf(ff[d], sW1[d * 64 + lane], h1);
    h1 = LRELU(h1);
    ex1[w][lane] = h1;
    __syncthreads();

    // layer 2: 32 outputs (both halves compute duplicates)
    const int c = lane & 31;
    float h2 = sB2[c];
#pragma unroll
    for (int d = 0; d < 64; ++d) h2 = fmaf(ex1[w][d], sW2[d * 32 + c], h2);
    h2 = LRELU(h2);
    if (lane < 32) ex2[w][c] = h2;
    __syncthreads();

    // layers 3+4: tiny, every lane computes the full thing
    float h3[4];
#pragma unroll
    for (int q = 0; q < 4; ++q) {
        float a = sB3[q];
#pragma unroll
        for (int d = 0; d < 32; ++d) a = fmaf(ex2[w][d], sW3[d * 4 + q], a);
        h3[q] = LRELU(a);
    }
    float o = sB4[0];
#pragma unroll
    for (int q = 0; q < 4; ++q) o = fmaf(h3[q], sW4[q], o);
    o = LRELU(o);

    if (lane == 0) dout[i] = o;                       // output 0: (8192,1)
    if (lane == 1) dout[N + i] = (float)bpfc[i];      // output 1: batch_pfc
}

// ---------------------------------------------------------------------------
extern "C" void kernel_launch(void* const* d_in, const int* in_sizes, int n_in,
                              void* d_out, int out_size, void* d_ws, size_t ws_size,
                              hipStream_t stream) {
    const float* x_pfc     = (const float*)d_in[0];
    const float* x_vtx     = (const float*)d_in[1];
    const int*   batch_pfc = (const int*)d_in[2];
    const int*   batch_vtx = (const int*)d_in[3];
    const float* pfc_w1 = (const float*)d_in[4];
    const float* pfc_b1 = (const float*)d_in[5];
    const float* pfc_w2 = (const float*)d_in[6];
    const float* pfc_b2 = (const float*)d_in[7];
    const float* vtx_w1 = (const float*)d_in[8];
    const float* vtx_b1 = (const float*)d_in[9];
    const float* vtx_w2 = (const float*)d_in[10];
    const float* vtx_b2 = (const float*)d_in[11];
    const float* conv_w = (const float*)d_in[12];
    const float* conv_b = (const float*)d_in[13];
    const float* out_w1 = (const float*)d_in[14];
    const float* out_b1 = (const float*)d_in[15];
    const float* out_w2 = (const float*)d_in[16];
    const float* out_b2 = (const float*)d_in[17];
    const float* out_w3 = (const float*)d_in[18];
    const float* out_b3 = (const float*)d_in[19];
    const float* out_w4 = (const float*)d_in[20];
    const float* out_b4 = (const float*)d_in[21];

    const int N_PFC = 8192, N_VTX = 2048;

    float* ws = (float*)d_ws;
    float* pfc_enc = ws;                 // 8192*32
    float* vtx_enc = ws + 262144;        // 2048*32
    float* feats1  = ws + 327680;        // 8192*32
    float* feats2  = ws + 589824;        // 8192*32
    float* n_pfc   = ws + 851968;        // 8192
    float* n_vtx   = ws + 860160;        // 2048
    float* n_f1    = ws + 862208;        // 8192

    encode_kernel<<<1280, 256, 0, stream>>>(x_pfc, x_vtx,
                                            pfc_w1, pfc_b1, pfc_w2, pfc_b2,
                                            vtx_w1, vtx_b1, vtx_w2, vtx_b2,
                                            pfc_enc, n_pfc, vtx_enc, n_vtx);

    // conv1: src = dst = pfc_enc (group sizes ~256±16, capacity 6*64=384)
    edge_conv_kernel<6, true><<<2048, 256, 0, stream>>>(
        pfc_enc, n_pfc, pfc_enc, n_pfc, batch_pfc, batch_pfc,
        N_PFC, N_PFC, conv_w, conv_b, feats1, n_f1);

    // conv2: dst = feats1 (batch_pfc), src = vtx_enc (~64±8/group, cap 192)
    edge_conv_kernel<3, false><<<2048, 256, 0, stream>>>(
        feats1, n_f1, vtx_enc, n_vtx, batch_pfc, batch_vtx,
        N_PFC, N_VTX, conv_w, conv_b, feats2, nullptr);

    out_mlp_kernel<<<2048, 256, 0, stream>>>(feats2, batch_pfc,
                                             out_w1, out_b1, out_w2, out_b2,
                                             out_w3, out_b3, out_w4, out_b4,
                                             (float*)d_out, N_PFC);
}

// Round 5
// 350.263 us; speedup vs baseline: 4.3163x; 1.2260x over previous
//
#include <hip/hip_runtime.h>
#include <hip/hip_bf16.h>

#define LRELU(val) ((val) >= 0.0f ? (val) : 0.01f * (val))

__device__ __forceinline__ float dot4(float4 a, float4 b, float acc) {
    return fmaf(a.x, b.x, fmaf(a.y, b.y, fmaf(a.z, b.z, fmaf(a.w, b.w, acc))));
}

// acc += quad `a` dotted with rows (4q..4q+3) of the 32-col weight slab at base
__device__ __forceinline__ float wdot4(const float* __restrict__ wbase, int c, int q,
                                       float4 a, float acc) {
    acc = fmaf(a.x, wbase[(4 * q + 0) * 32 + c], acc);
    acc = fmaf(a.y, wbase[(4 * q + 1) * 32 + c], acc);
    acc = fmaf(a.z, wbase[(4 * q + 2) * 32 + c], acc);
    acc = fmaf(a.w, wbase[(4 * q + 3) * 32 + c], acc);
    return acc;
}

__device__ __forceinline__ float4 sub4(float4 a, float4 b) {
    return make_float4(a.x - b.x, a.y - b.y, a.z - b.z, a.w - b.w);
}

__device__ inline int lower_bound_i(const int* __restrict__ a, int n, int v) {
    int lo = 0, hi = n;
    while (lo < hi) {
        int m = (lo + hi) >> 1;
        if (a[m] < v) lo = m + 1; else hi = m;
    }
    return lo;
}

// ---------------------------------------------------------------------------
// Kernel 1: both MLP2 encoders (pfc: 7->32->32, vtx: 4->32->32) + sq norms.
// ---------------------------------------------------------------------------
__launch_bounds__(256)
__global__ void encode_kernel(const float* __restrict__ x_pfc, const float* __restrict__ x_vtx,
                              const float* __restrict__ pw1, const float* __restrict__ pb1,
                              const float* __restrict__ pw2, const float* __restrict__ pb2,
                              const float* __restrict__ vw1, const float* __restrict__ vb1,
                              const float* __restrict__ vw2, const float* __restrict__ vb2,
                              float* __restrict__ pfc_enc, float* __restrict__ pfc_norm,
                              float* __restrict__ vtx_enc, float* __restrict__ vtx_norm) {
    __shared__ float h1s[8][32];
    const int t = threadIdx.x;
    const int c = t & 31;
    const int nl = t >> 5;

    const bool is_pfc = (blockIdx.x < 1024);
    const int node = (is_pfc ? blockIdx.x : (blockIdx.x - 1024)) * 8 + nl;
    const int din = is_pfc ? 7 : 4;
    const float* __restrict__ xin = is_pfc ? (x_pfc + node * 7) : (x_vtx + node * 4);
    const float* __restrict__ w1 = is_pfc ? pw1 : vw1;
    const float* __restrict__ b1 = is_pfc ? pb1 : vb1;
    const float* __restrict__ w2 = is_pfc ? pw2 : vw2;
    const float* __restrict__ b2 = is_pfc ? pb2 : vb2;
    float* __restrict__ enc  = is_pfc ? pfc_enc : vtx_enc;
    float* __restrict__ nrm  = is_pfc ? pfc_norm : vtx_norm;

    float h1 = b1[c];
    for (int d = 0; d < din; ++d) h1 = fmaf(xin[d], w1[d * 32 + c], h1);
    h1 = LRELU(h1);
    h1s[nl][c] = h1;
    __syncthreads();

    float h2 = b2[c];
#pragma unroll
    for (int d = 0; d < 32; ++d) h2 = fmaf(h1s[nl][d], w2[d * 32 + c], h2);
    h2 = LRELU(h2);
    enc[node * 32 + c] = h2;

    float s = h2 * h2;
#pragma unroll
    for (int m = 16; m >= 1; m >>= 1) s += __shfl_xor(s, m);
    if (c == 0) nrm[node] = s;
}

// ---------------------------------------------------------------------------
// Kernel 2/3: fused kNN(K=16, group-local) + edge conv + max-pool.
// One wave per dst node, 4 waves/block. NO private arrays anywhere (rounds
// 1-3: alloca-demotion to scratch cost 0.5-1.7 GB of HBM traffic). Per-lane
// state is named float4s/scalars; distances live in a per-wave LDS buffer,
// written once then READ-ONLY. Selection round k picks the lex-smallest
// (d, idx) strictly greater than round k-1's winner — identical result to
// argmin-with-invalidation, and needs no LDS writes during selection.
// ---------------------------------------------------------------------------
template <int MAXS, bool WRITE_NORM>
__launch_bounds__(256)
__global__ void edge_conv_kernel(const float* __restrict__ dstf, const float* __restrict__ dstn,
                                 const float* __restrict__ srcf, const float* __restrict__ srcn,
                                 const int* __restrict__ bdst, const int* __restrict__ bsrc,
                                 int Nd, int Ns,
                                 const float* __restrict__ W, const float* __restrict__ B,
                                 float* __restrict__ outf, float* __restrict__ outn) {
    __shared__ float sW[64 * 32];
    __shared__ float sB[32];
    __shared__ float sDist[4][MAXS];
    __shared__ int   widx[4][16];

    const int t = threadIdx.x;
    const int lane = t & 63;
    const int w = t >> 6;
    const int i = blockIdx.x * 4 + w;   // grid exactly covers Nd (Nd % 4 == 0)

    for (int k = t; k < 2048; k += 256) sW[k] = W[k];
    if (t < 32) sB[t] = B[t];
    __syncthreads();

    const int g = bdst[i];
    const int start = lower_bound_i(bsrc, Ns, g);
    const int end   = lower_bound_i(bsrc, Ns, g + 1);
    const int len   = min(end - start, MAXS);   // MAXS >> 8 sigma of group size
    const float ni  = dstn[i];
    const float FINF = __builtin_huge_valf();

    // dst features: 8 named float4s (wave-uniform broadcast loads)
    const float4* xr = reinterpret_cast<const float4*>(dstf + (size_t)i * 32);
    const float4 xi0 = xr[0], xi1 = xr[1], xi2 = xr[2], xi3 = xr[3],
                 xi4 = xr[4], xi5 = xr[5], xi6 = xr[6], xi7 = xr[7];

    // Phase 1: distances -> LDS.  d2 = |dst|^2 + |src|^2 - 2*dot (ref formula)
#pragma unroll 1
    for (int s = lane; s < len; s += 64) {
        const float4* rr = reinterpret_cast<const float4*>(srcf + (size_t)(start + s) * 32);
        float dot = 0.0f;
        dot = dot4(rr[0], xi0, dot); dot = dot4(rr[1], xi1, dot);
        dot = dot4(rr[2], xi2, dot); dot = dot4(rr[3], xi3, dot);
        dot = dot4(rr[4], xi4, dot); dot = dot4(rr[5], xi5, dot);
        dot = dot4(rr[6], xi6, dot); dot = dot4(rr[7], xi7, dot);
        sDist[w][s] = ni + srcn[start + s] - 2.0f * dot;
    }
    __syncthreads();

    // Phase 2: 16 selection rounds over the read-only LDS distances.
    float pd = -FINF;        // previous winner (distance, index)
    int   pi = -1;
#pragma unroll 1
    for (int k = 0; k < 16; ++k) {
        float bd = FINF;
        int   bi = 0x7fffffff;
#pragma unroll 1
        for (int s = lane; s < len; s += 64) {
            float d = sDist[w][s];
            int idx = start + s;
            bool ok = (d > pd) || (d == pd && idx > pi);
            if (ok && (d < bd || (d == bd && idx < bi))) { bd = d; bi = idx; }
        }
#pragma unroll
        for (int m = 32; m >= 1; m >>= 1) {
            float od = __shfl_xor(bd, m);
            int   oi = __shfl_xor(bi, m);
            if (od < bd || (od == bd && oi < bi)) { bd = od; bi = oi; }
        }
        pd = bd; pi = bi;
        if (lane == 0) widx[w][k] = bi;
    }
    __syncthreads();   // make widx visible (uniform: every wave runs 16 rounds)

    // base[c] = b[c] + sum_d xi[d]*W[d][c]  (first 32 rows of W)
    const int c = lane & 31;
    float base = sB[c];
    base = wdot4(sW, c, 0, xi0, base); base = wdot4(sW, c, 1, xi1, base);
    base = wdot4(sW, c, 2, xi2, base); base = wdot4(sW, c, 3, xi3, base);
    base = wdot4(sW, c, 4, xi4, base); base = wdot4(sW, c, 5, xi5, base);
    base = wdot4(sW, c, 6, xi6, base); base = wdot4(sW, c, 7, xi7, base);

    // Phase 3: conv, two neighbors per round (half-wave each)
    const int half = lane >> 5;
    const float* sW2nd = sW + 32 * 32;   // rows 32..63 (the x_j - x_i part)
    float vmax = -FINF;
#pragma unroll 1
    for (int r = 0; r < 8; ++r) {
        int bi = widx[w][2 * r + half];
        int j = ((unsigned)bi < (unsigned)Ns) ? bi : min(start, Ns - 1);  // clamp (len<16 ~ impossible)
        const float4* rr = reinterpret_cast<const float4*>(srcf + (size_t)j * 32);
        float acc = base;
        acc = wdot4(sW2nd, c, 0, sub4(rr[0], xi0), acc);
        acc = wdot4(sW2nd, c, 1, sub4(rr[1], xi1), acc);
        acc = wdot4(sW2nd, c, 2, sub4(rr[2], xi2), acc);
        acc = wdot4(sW2nd, c, 3, sub4(rr[3], xi3), acc);
        acc = wdot4(sW2nd, c, 4, sub4(rr[4], xi4), acc);
        acc = wdot4(sW2nd, c, 5, sub4(rr[5], xi5), acc);
        acc = wdot4(sW2nd, c, 6, sub4(rr[6], xi6), acc);
        acc = wdot4(sW2nd, c, 7, sub4(rr[7], xi7), acc);
        vmax = fmaxf(vmax, LRELU(acc));
    }
    vmax = fmaxf(vmax, __shfl_xor(vmax, 32));  // combine the two halves

    if (lane < 32) outf[(size_t)i * 32 + c] = vmax;
    if (WRITE_NORM) {
        float s2 = vmax * vmax;
#pragma unroll
        for (int m = 16; m >= 1; m >>= 1) s2 += __shfl_xor(s2, m);
        if (lane == 0) outn[i] = s2;
    }
}

// ---------------------------------------------------------------------------
// Kernel 4: output MLP 32 -> 64 -> 32 -> 4 -> 1 (lrelu each) + batch copy.
// ---------------------------------------------------------------------------
__launch_bounds__(256)
__global__ void out_mlp_kernel(const float* __restrict__ f2, const int* __restrict__ bpfc,
                               const float* __restrict__ w1, const float* __restrict__ b1,
                               const float* __restrict__ w2, const float* __restrict__ b2,
                               const float* __restrict__ w3, const float* __restrict__ b3,
                               const float* __restrict__ w4, const float* __restrict__ b4,
                               float* __restrict__ dout, int N) {
    __shared__ float sW1[32 * 64], sW2[64 * 32], sW3[32 * 4];
    __shared__ float sB1[64], sB2[32], sB3[4], sW4[4], sB4[1];
    __shared__ float ex1[4][64];
    __shared__ float ex2[4][32];

    const int t = threadIdx.x;
    for (int k = t; k < 2048; k += 256) { sW1[k] = w1[k]; sW2[k] = w2[k]; }
    if (t < 128) sW3[t] = w3[t];
    if (t < 64)  sB1[t] = b1[t];
    if (t < 32)  sB2[t] = b2[t];
    if (t < 4)   { sB3[t] = b3[t]; sW4[t] = w4[t]; }
    if (t == 0)  sB4[0] = b4[0];
    __syncthreads();

    const int w = t >> 6;
    const int lane = t & 63;
    const int i = blockIdx.x * 4 + w;

    const float* fr = f2 + (size_t)i * 32;

    // layer 1: 64 outputs, one per lane
    float h1 = sB1[lane];
#pragma unroll
    for (int d = 0; d < 32; ++d) h1 = fmaf(fr[d], sW1[d * 64 + lane], h1);
    h1 = LRELU(h1);
    ex1[w][lane] = h1;
    __syncthreads();

    // layer 2: 32 outputs (both halves compute duplicates)
    const int c = lane & 31;
    float h2 = sB2[c];
#pragma unroll
    for (int d = 0; d < 64; ++d) h2 = fmaf(ex1[w][d], sW2[d * 32 + c], h2);
    h2 = LRELU(h2);
    if (lane < 32) ex2[w][c] = h2;
    __syncthreads();

    // layers 3+4
    float a0 = sB3[0], a1 = sB3[1], a2 = sB3[2], a3 = sB3[3];
#pragma unroll
    for (int d = 0; d < 32; ++d) {
        float e = ex2[w][d];
        a0 = fmaf(e, sW3[d * 4 + 0], a0);
        a1 = fmaf(e, sW3[d * 4 + 1], a1);
        a2 = fmaf(e, sW3[d * 4 + 2], a2);
        a3 = fmaf(e, sW3[d * 4 + 3], a3);
    }
    a0 = LRELU(a0); a1 = LRELU(a1); a2 = LRELU(a2); a3 = LRELU(a3);
    float o = sB4[0];
    o = fmaf(a0, sW4[0], o); o = fmaf(a1, sW4[1], o);
    o = fmaf(a2, sW4[2], o); o = fmaf(a3, sW4[3], o);
    o = LRELU(o);

    if (lane == 0) dout[i] = o;                       // output 0: (8192,1)
    if (lane == 1) dout[N + i] = (float)bpfc[i];      // output 1: batch_pfc
}

// ---------------------------------------------------------------------------
extern "C" void kernel_launch(void* const* d_in, const int* in_sizes, int n_in,
                              void* d_out, int out_size, void* d_ws, size_t ws_size,
                              hipStream_t stream) {
    const float* x_pfc     = (const float*)d_in[0];
    const float* x_vtx     = (const float*)d_in[1];
    const int*   batch_pfc = (const int*)d_in[2];
    const int*   batch_vtx = (const int*)d_in[3];
    const float* pfc_w1 = (const float*)d_in[4];
    const float* pfc_b1 = (const float*)d_in[5];
    const float* pfc_w2 = (const float*)d_in[6];
    const float* pfc_b2 = (const float*)d_in[7];
    const float* vtx_w1 = (const float*)d_in[8];
    const float* vtx_b1 = (const float*)d_in[9];
    const float* vtx_w2 = (const float*)d_in[10];
    const float* vtx_b2 = (const float*)d_in[11];
    const float* conv_w = (const float*)d_in[12];
    const float* conv_b = (const float*)d_in[13];
    const float* out_w1 = (const float*)d_in[14];
    const float* out_b1 = (const float*)d_in[15];
    const float* out_w2 = (const float*)d_in[16];
    const float* out_b2 = (const float*)d_in[17];
    const float* out_w3 = (const float*)d_in[18];
    const float* out_b3 = (const float*)d_in[19];
    const float* out_w4 = (const float*)d_in[20];
    const float* out_b4 = (const float*)d_in[21];

    const int N_PFC = 8192, N_VTX = 2048;

    float* ws = (float*)d_ws;
    float* pfc_enc = ws;                 // 8192*32
    float* vtx_enc = ws + 262144;        // 2048*32
    float* feats1  = ws + 327680;        // 8192*32
    float* feats2  = ws + 589824;        // 8192*32
    float* n_pfc   = ws + 851968;        // 8192
    float* n_vtx   = ws + 860160;        // 2048
    float* n_f1    = ws + 862208;        // 8192

    encode_kernel<<<1280, 256, 0, stream>>>(x_pfc, x_vtx,
                                            pfc_w1, pfc_b1, pfc_w2, pfc_b2,
                                            vtx_w1, vtx_b1, vtx_w2, vtx_b2,
                                            pfc_enc, n_pfc, vtx_enc, n_vtx);

    // conv1: src = dst = pfc_enc (group sizes ~256±16; MAXS=512 covers 16 sigma)
    edge_conv_kernel<512, true><<<2048, 256, 0, stream>>>(
        pfc_enc, n_pfc, pfc_enc, n_pfc, batch_pfc, batch_pfc,
        N_PFC, N_PFC, conv_w, conv_b, feats1, n_f1);

    // conv2: dst = feats1 (batch_pfc), src = vtx_enc (~64±8/group; MAXS=128)
    edge_conv_kernel<128, false><<<2048, 256, 0, stream>>>(
        feats1, n_f1, vtx_enc, n_vtx, batch_pfc, batch_vtx,
        N_PFC, N_VTX, conv_w, conv_b, feats2, nullptr);

    out_mlp_kernel<<<2048, 256, 0, stream>>>(feats2, batch_pfc,
                                             out_w1, out_b1, out_w2, out_b2,
                                             out_w3, out_b3, out_w4, out_b4,
                                             (float*)d_out, N_PFC);
}

// Round 6
// 258.812 us; speedup vs baseline: 5.8414x; 1.3533x over previous
//
#include <hip/hip_runtime.h>
#include <hip/hip_bf16.h>

#define LRELU(val) ((val) >= 0.0f ? (val) : 0.01f * (val))

__device__ __forceinline__ float dot4(float4 a, float4 b, float acc) {
    return fmaf(a.x, b.x, fmaf(a.y, b.y, fmaf(a.z, b.z, fmaf(a.w, b.w, acc))));
}

// acc += quad `a` dotted with rows (4q..4q+3) of the 32-col weight slab
__device__ __forceinline__ float wdot4(const float* __restrict__ wbase, int c, int q,
                                       float4 a, float acc) {
    acc = fmaf(a.x, wbase[(4 * q + 0) * 32 + c], acc);
    acc = fmaf(a.y, wbase[(4 * q + 1) * 32 + c], acc);
    acc = fmaf(a.z, wbase[(4 * q + 2) * 32 + c], acc);
    acc = fmaf(a.w, wbase[(4 * q + 3) * 32 + c], acc);
    return acc;
}

__device__ __forceinline__ float4 sub4(float4 a, float4 b) {
    return make_float4(a.x - b.x, a.y - b.y, a.z - b.z, a.w - b.w);
}

__device__ inline int lower_bound_i(const int* __restrict__ a, int n, int v) {
    int lo = 0, hi = n;
    while (lo < hi) {
        int m = (lo + hi) >> 1;
        if (a[m] < v) lo = m + 1; else hi = m;
    }
    return lo;
}

// ---------------------------------------------------------------------------
// Kernel 1: both MLP2 encoders + sq norms + group-offset tables (33 entries
// each; kills the per-wave binary searches in the conv kernels).
// ---------------------------------------------------------------------------
__launch_bounds__(256)
__global__ void encode_kernel(const float* __restrict__ x_pfc, const float* __restrict__ x_vtx,
                              const int* __restrict__ bpfc, const int* __restrict__ bvtx,
                              const float* __restrict__ pw1, const float* __restrict__ pb1,
                              const float* __restrict__ pw2, const float* __restrict__ pb2,
                              const float* __restrict__ vw1, const float* __restrict__ vb1,
                              const float* __restrict__ vw2, const float* __restrict__ vb2,
                              float* __restrict__ pfc_enc, float* __restrict__ pfc_norm,
                              float* __restrict__ vtx_enc, float* __restrict__ vtx_norm,
                              int* __restrict__ goff_pfc, int* __restrict__ goff_vtx) {
    __shared__ float h1s[8][32];
    const int t = threadIdx.x;
    const int c = t & 31;
    const int nl = t >> 5;

    if (blockIdx.x == 0) {
        if (t < 33) goff_pfc[t] = lower_bound_i(bpfc, 8192, t);
        else if (t >= 64 && t < 97) goff_vtx[t - 64] = lower_bound_i(bvtx, 2048, t - 64);
    }

    const bool is_pfc = (blockIdx.x < 1024);
    const int node = (is_pfc ? blockIdx.x : (blockIdx.x - 1024)) * 8 + nl;
    const int din = is_pfc ? 7 : 4;
    const float* __restrict__ xin = is_pfc ? (x_pfc + node * 7) : (x_vtx + node * 4);
    const float* __restrict__ w1 = is_pfc ? pw1 : vw1;
    const float* __restrict__ b1 = is_pfc ? pb1 : vb1;
    const float* __restrict__ w2 = is_pfc ? pw2 : vw2;
    const float* __restrict__ b2 = is_pfc ? pb2 : vb2;
    float* __restrict__ enc  = is_pfc ? pfc_enc : vtx_enc;
    float* __restrict__ nrm  = is_pfc ? pfc_norm : vtx_norm;

    float h1 = b1[c];
    for (int d = 0; d < din; ++d) h1 = fmaf(xin[d], w1[d * 32 + c], h1);
    h1 = LRELU(h1);
    h1s[nl][c] = h1;
    __syncthreads();

    float h2 = b2[c];
#pragma unroll
    for (int d = 0; d < 32; ++d) h2 = fmaf(h1s[nl][d], w2[d * 32 + c], h2);
    h2 = LRELU(h2);
    enc[node * 32 + c] = h2;

    float s = h2 * h2;
#pragma unroll
    for (int m = 16; m >= 1; m >>= 1) s += __shfl_xor(s, m);
    if (c == 0) nrm[node] = s;
}

// ---------------------------------------------------------------------------
// Kernel 2/3: fused kNN(K=16) + edge conv + max-pool.  One wave per dst node.
// Selection is SHUFFLE-FREE rank-counting: unique sortable key per candidate
// (key = sortable(d2)<<32 | idx, idx-tiebroken exactly like lax.top_k);
// rank(s) = #{t: key_t < key_s}; ranks 0..15 are the neighbors. The count
// loop is pure throughput (LDS broadcast read + cmp_u64/addc), no dependent
// cross-lane chains (round-5: 16 sequential 6-step butterflies stalled at
// VALUBusy 25%). Neighbor rows staged to LDS (2 indep loads/lane) before the
// conv (kills the 8-round dependent global-fetch chain). No private arrays
// anywhere (rounds 1-3: alloca scratch = 0.5-1.7 GB HBM traffic).
// ---------------------------------------------------------------------------
template <int MAXS, bool WRITE_NORM>
__launch_bounds__(256)
__global__ void edge_conv_kernel(const float* __restrict__ dstf, const float* __restrict__ dstn,
                                 const float* __restrict__ srcf, const float* __restrict__ srcn,
                                 const int* __restrict__ bdst, const int* __restrict__ goff,
                                 int Nd, int Ns,
                                 const float* __restrict__ W, const float* __restrict__ B,
                                 float* __restrict__ outf, float* __restrict__ outn) {
    constexpr int SLOTS = MAXS / 64;
    __shared__ float sW[64 * 32];
    __shared__ float sB[32];
    __shared__ unsigned long long sKey[4][MAXS];
    __shared__ float4 sNbr[4][16][8];
    __shared__ int widx[4][16];

    const int t = threadIdx.x;
    const int lane = t & 63;
    const int w = t >> 6;
    const int i = blockIdx.x * 4 + w;   // grid exactly covers Nd (Nd % 4 == 0)

    for (int k = t; k < 2048; k += 256) sW[k] = W[k];
    if (t < 32) sB[t] = B[t];
    __syncthreads();

    const int g = bdst[i];
    const int start = goff[g];
    const int end   = goff[g + 1];
    const int len   = min(end - start, MAXS);   // MAXS is >8 sigma of group size
    const float ni  = dstn[i];
    const float FINF = __builtin_huge_valf();
    const unsigned long long KMAX = ~0ull;

    // dst features: 8 named float4s (wave-uniform broadcast loads)
    const float4* xr = reinterpret_cast<const float4*>(dstf + (size_t)i * 32);
    const float4 xi0 = xr[0], xi1 = xr[1], xi2 = xr[2], xi3 = xr[3],
                 xi4 = xr[4], xi5 = xr[5], xi6 = xr[6], xi7 = xr[7];

    // Phase 1: distance keys -> LDS.  d2 = (ni + nj) - 2*dot (ref formula)
#pragma unroll 1
    for (int s = lane; s < len; s += 64) {
        const float4* rr = reinterpret_cast<const float4*>(srcf + (size_t)(start + s) * 32);
        float dot = 0.0f;
        dot = dot4(rr[0], xi0, dot); dot = dot4(rr[1], xi1, dot);
        dot = dot4(rr[2], xi2, dot); dot = dot4(rr[3], xi3, dot);
        dot = dot4(rr[4], xi4, dot); dot = dot4(rr[5], xi5, dot);
        dot = dot4(rr[6], xi6, dot); dot = dot4(rr[7], xi7, dot);
        float d2 = (ni + srcn[start + s]) - 2.0f * dot;
        unsigned u = __float_as_uint(d2);
        u = (d2 < 0.0f) ? ~u : (u | 0x80000000u);
        sKey[w][s] = ((unsigned long long)u << 32) | (unsigned)(start + s);
    }
    __syncthreads();

    // Own keys into named registers (constant slot indices — no arrays)
    unsigned long long k0 = KMAX, k1 = KMAX, k2 = KMAX, k3 = KMAX, k4 = KMAX, k5 = KMAX;
    if (SLOTS > 0 && lane + 0 * 64 < len) k0 = sKey[w][lane + 0 * 64];
    if (SLOTS > 1 && lane + 1 * 64 < len) k1 = sKey[w][lane + 1 * 64];
    if (SLOTS > 2 && lane + 2 * 64 < len) k2 = sKey[w][lane + 2 * 64];
    if (SLOTS > 3 && lane + 3 * 64 < len) k3 = sKey[w][lane + 3 * 64];
    if (SLOTS > 4 && lane + 4 * 64 < len) k4 = sKey[w][lane + 4 * 64];
    if (SLOTS > 5 && lane + 5 * 64 < len) k5 = sKey[w][lane + 5 * 64];

    // Phase 2: rank counting — pure throughput, no cross-lane ops.
    int r0 = 0, r1 = 0, r2 = 0, r3 = 0, r4 = 0, r5 = 0;
#pragma unroll 2
    for (int tt = 0; tt < len; ++tt) {
        unsigned long long kt = sKey[w][tt];
        r0 += (kt < k0);
        if (SLOTS > 1) r1 += (kt < k1);
        if (SLOTS > 2) r2 += (kt < k2);
        if (SLOTS > 3) r3 += (kt < k3);
        if (SLOTS > 4) r4 += (kt < k4);
        if (SLOTS > 5) r5 += (kt < k5);
    }

    // Scatter winners (ranks are unique — keys are unique)
    if (lane < 16) widx[w][lane] = start;   // fallback for len<16 (never in practice)
    if (SLOTS > 0 && r0 < 16 && lane + 0 * 64 < len) widx[w][r0] = start + lane + 0 * 64;
    if (SLOTS > 1 && r1 < 16 && lane + 1 * 64 < len) widx[w][r1] = start + lane + 1 * 64;
    if (SLOTS > 2 && r2 < 16 && lane + 2 * 64 < len) widx[w][r2] = start + lane + 2 * 64;
    if (SLOTS > 3 && r3 < 16 && lane + 3 * 64 < len) widx[w][r3] = start + lane + 3 * 64;
    if (SLOTS > 4 && r4 < 16 && lane + 4 * 64 < len) widx[w][r4] = start + lane + 4 * 64;
    if (SLOTS > 5 && r5 < 16 && lane + 5 * 64 < len) widx[w][r5] = start + lane + 5 * 64;
    __syncthreads();

    // Stage the 16 neighbor rows into LDS: 128 float4s, 2 indep loads/lane.
#pragma unroll 1
    for (int p = lane; p < 128; p += 64) {
        int n = p >> 3, q = p & 7;
        int j = widx[w][n];
        j = ((unsigned)j < (unsigned)Ns) ? j : 0;  // safety clamp
        sNbr[w][n][q] = reinterpret_cast<const float4*>(srcf + (size_t)j * 32)[q];
    }
    __syncthreads();

    // base[c] = b[c] + sum_d xi[d]*W[d][c]  (first 32 rows of W)
    const int c = lane & 31;
    float base = sB[c];
    base = wdot4(sW, c, 0, xi0, base); base = wdot4(sW, c, 1, xi1, base);
    base = wdot4(sW, c, 2, xi2, base); base = wdot4(sW, c, 3, xi3, base);
    base = wdot4(sW, c, 4, xi4, base); base = wdot4(sW, c, 5, xi5, base);
    base = wdot4(sW, c, 6, xi6, base); base = wdot4(sW, c, 7, xi7, base);

    // Phase 3: conv from LDS, two neighbors per round (half-wave each)
    const int half = lane >> 5;
    const float* sW2nd = sW + 32 * 32;   // rows 32..63 (the x_j - x_i part)
    float vmax = -FINF;
#pragma unroll 1
    for (int r = 0; r < 8; ++r) {
        const float4* nb = sNbr[w][2 * r + half];
        float acc = base;
        acc = wdot4(sW2nd, c, 0, sub4(nb[0], xi0), acc);
        acc = wdot4(sW2nd, c, 1, sub4(nb[1], xi1), acc);
        acc = wdot4(sW2nd, c, 2, sub4(nb[2], xi2), acc);
        acc = wdot4(sW2nd, c, 3, sub4(nb[3], xi3), acc);
        acc = wdot4(sW2nd, c, 4, sub4(nb[4], xi4), acc);
        acc = wdot4(sW2nd, c, 5, sub4(nb[5], xi5), acc);
        acc = wdot4(sW2nd, c, 6, sub4(nb[6], xi6), acc);
        acc = wdot4(sW2nd, c, 7, sub4(nb[7], xi7), acc);
        vmax = fmaxf(vmax, LRELU(acc));
    }
    vmax = fmaxf(vmax, __shfl_xor(vmax, 32));  // combine the two halves

    if (lane < 32) outf[(size_t)i * 32 + c] = vmax;
    if (WRITE_NORM) {
        float s2 = vmax * vmax;
#pragma unroll
        for (int m = 16; m >= 1; m >>= 1) s2 += __shfl_xor(s2, m);
        if (lane == 0) outn[i] = s2;
    }
}

// ---------------------------------------------------------------------------
// Kernel 4: output MLP 32 -> 64 -> 32 -> 4 -> 1 (lrelu each) + batch copy.
// ---------------------------------------------------------------------------
__launch_bounds__(256)
__global__ void out_mlp_kernel(const float* __restrict__ f2, const int* __restrict__ bpfc,
                               const float* __restrict__ w1, const float* __restrict__ b1,
                               const float* __restrict__ w2, const float* __restrict__ b2,
                               const float* __restrict__ w3, const float* __restrict__ b3,
                               const float* __restrict__ w4, const float* __restrict__ b4,
                               float* __restrict__ dout, int N) {
    __shared__ float sW1[32 * 64], sW2[64 * 32], sW3[32 * 4];
    __shared__ float sB1[64], sB2[32], sB3[4], sW4[4], sB4[1];
    __shared__ float ex1[4][64];
    __shared__ float ex2[4][32];

    const int t = threadIdx.x;
    for (int k = t; k < 2048; k += 256) { sW1[k] = w1[k]; sW2[k] = w2[k]; }
    if (t < 128) sW3[t] = w3[t];
    if (t < 64)  sB1[t] = b1[t];
    if (t < 32)  sB2[t] = b2[t];
    if (t < 4)   { sB3[t] = b3[t]; sW4[t] = w4[t]; }
    if (t == 0)  sB4[0] = b4[0];
    __syncthreads();

    const int w = t >> 6;
    const int lane = t & 63;
    const int i = blockIdx.x * 4 + w;

    const float* fr = f2 + (size_t)i * 32;

    float h1 = sB1[lane];
#pragma unroll
    for (int d = 0; d < 32; ++d) h1 = fmaf(fr[d], sW1[d * 64 + lane], h1);
    h1 = LRELU(h1);
    ex1[w][lane] = h1;
    __syncthreads();

    const int c = lane & 31;
    float h2 = sB2[c];
#pragma unroll
    for (int d = 0; d < 64; ++d) h2 = fmaf(ex1[w][d], sW2[d * 32 + c], h2);
    h2 = LRELU(h2);
    if (lane < 32) ex2[w][c] = h2;
    __syncthreads();

    float a0 = sB3[0], a1 = sB3[1], a2 = sB3[2], a3 = sB3[3];
#pragma unroll
    for (int d = 0; d < 32; ++d) {
        float e = ex2[w][d];
        a0 = fmaf(e, sW3[d * 4 + 0], a0);
        a1 = fmaf(e, sW3[d * 4 + 1], a1);
        a2 = fmaf(e, sW3[d * 4 + 2], a2);
        a3 = fmaf(e, sW3[d * 4 + 3], a3);
    }
    a0 = LRELU(a0); a1 = LRELU(a1); a2 = LRELU(a2); a3 = LRELU(a3);
    float o = sB4[0];
    o = fmaf(a0, sW4[0], o); o = fmaf(a1, sW4[1], o);
    o = fmaf(a2, sW4[2], o); o = fmaf(a3, sW4[3], o);
    o = LRELU(o);

    if (lane == 0) dout[i] = o;                       // output 0: (8192,1)
    if (lane == 1) dout[N + i] = (float)bpfc[i];      // output 1: batch_pfc
}

// ---------------------------------------------------------------------------
extern "C" void kernel_launch(void* const* d_in, const int* in_sizes, int n_in,
                              void* d_out, int out_size, void* d_ws, size_t ws_size,
                              hipStream_t stream) {
    const float* x_pfc     = (const float*)d_in[0];
    const float* x_vtx     = (const float*)d_in[1];
    const int*   batch_pfc = (const int*)d_in[2];
    const int*   batch_vtx = (const int*)d_in[3];
    const float* pfc_w1 = (const float*)d_in[4];
    const float* pfc_b1 = (const float*)d_in[5];
    const float* pfc_w2 = (const float*)d_in[6];
    const float* pfc_b2 = (const float*)d_in[7];
    const float* vtx_w1 = (const float*)d_in[8];
    const float* vtx_b1 = (const float*)d_in[9];
    const float* vtx_w2 = (const float*)d_in[10];
    const float* vtx_b2 = (const float*)d_in[11];
    const float* conv_w = (const float*)d_in[12];
    const float* conv_b = (const float*)d_in[13];
    const float* out_w1 = (const float*)d_in[14];
    const float* out_b1 = (const float*)d_in[15];
    const float* out_w2 = (const float*)d_in[16];
    const float* out_b2 = (const float*)d_in[17];
    const float* out_w3 = (const float*)d_in[18];
    const float* out_b3 = (const float*)d_in[19];
    const float* out_w4 = (const float*)d_in[20];
    const float* out_b4 = (const float*)d_in[21];

    const int N_PFC = 8192, N_VTX = 2048;

    float* ws = (float*)d_ws;
    float* pfc_enc = ws;                 // 8192*32
    float* vtx_enc = ws + 262144;        // 2048*32
    float* feats1  = ws + 327680;        // 8192*32
    float* feats2  = ws + 589824;        // 8192*32
    float* n_pfc   = ws + 851968;        // 8192
    float* n_vtx   = ws + 860160;        // 2048
    float* n_f1    = ws + 862208;        // 8192
    int*   goff_pfc = (int*)(ws + 870400);   // 33
    int*   goff_vtx = (int*)(ws + 870464);   // 33

    encode_kernel<<<1280, 256, 0, stream>>>(x_pfc, x_vtx, batch_pfc, batch_vtx,
                                            pfc_w1, pfc_b1, pfc_w2, pfc_b2,
                                            vtx_w1, vtx_b1, vtx_w2, vtx_b2,
                                            pfc_enc, n_pfc, vtx_enc, n_vtx,
                                            goff_pfc, goff_vtx);

    // conv1: src = dst = pfc_enc (group ~256±16; MAXS=384 covers >8 sigma)
    edge_conv_kernel<384, true><<<2048, 256, 0, stream>>>(
        pfc_enc, n_pfc, pfc_enc, n_pfc, batch_pfc, goff_pfc,
        N_PFC, N_PFC, conv_w, conv_b, feats1, n_f1);

    // conv2: dst = feats1 (batch_pfc), src = vtx_enc (~64±8/group; MAXS=128)
    edge_conv_kernel<128, false><<<2048, 256, 0, stream>>>(
        feats1, n_f1, vtx_enc, n_vtx, batch_pfc, goff_vtx,
        N_PFC, N_VTX, conv_w, conv_b, feats2, nullptr);

    out_mlp_kernel<<<2048, 256, 0, stream>>>(feats2, batch_pfc,
                                             out_w1, out_b1, out_w2, out_b2,
                                             out_w3, out_b3, out_w4, out_b4,
                                             (float*)d_out, N_PFC);
}